// Round 30
// baseline (219.623 us; speedup 1.0000x reference)
//
#include <hip/hip_runtime.h>
#include <hip/hip_bf16.h>
#include <math.h>

#define TSEQ 2048
#define BATCH 2
#define CDIM 1024
#define NH 16
#define HD 64
#define DFF 4096
#define ROWS (BATCH*TSEQ)   // 4096

typedef __attribute__((ext_vector_type(4))) float f32x4;
typedef __attribute__((ext_vector_type(8))) short bf16x8;   // 8 bf16 in 4 VGPRs
typedef __attribute__((ext_vector_type(4))) unsigned short u16x4;

__device__ __forceinline__ void gload_lds16(const void* g, void* l) {
    void* gv = const_cast<void*>(g);
    __builtin_amdgcn_global_load_lds((__attribute__((address_space(1))) void*)gv,
                                     (__attribute__((address_space(3))) void*)l, 16, 0, 0);
}

__device__ __forceinline__ unsigned short f2bf(float f) {
    unsigned int u = __float_as_uint(f);
    return (unsigned short)((u + 0x7FFFu + ((u >> 16) & 1u)) >> 16);
}
__device__ __forceinline__ float bf2f(unsigned short u) {
    return __uint_as_float((unsigned int)u << 16);
}
// packed f32x2 -> bf16x2 (low half = first arg); no builtin on gfx950 (T12)
__device__ __forceinline__ unsigned int cvt_pk_bf16(float lo, float hi) {
    unsigned int r;
    asm("v_cvt_pk_bf16_f32 %0, %1, %2" : "=v"(r) : "v"(lo), "v"(hi));
    return r;
}
// tanh-form GELU: v * sigmoid(1.59577*(v + 0.044715 v^3)); |err vs exact| < ~3e-4
__device__ __forceinline__ float fast_gelu(float v) {
    float u = fmaf(0.044715f * v * v, v, v);
    float e = __expf(-1.5957691216057308f * u);
    return v * __builtin_amdgcn_rcpf(1.0f + e);
}

// ------------------------------- LayerNorm -> bf16 --------------------------------
__global__ __launch_bounds__(256) void ln_kernel(const float* __restrict__ x,
                                                 const float* __restrict__ g,
                                                 const float* __restrict__ b,
                                                 unsigned short* __restrict__ out) {
    int row = blockIdx.x;
    int tid = threadIdx.x;
    const float* xr = x + (size_t)row * CDIM;
    float4 v = *(const float4*)(xr + tid * 4);
    float s  = v.x + v.y + v.z + v.w;
    float s2 = v.x*v.x + v.y*v.y + v.z*v.z + v.w*v.w;
    #pragma unroll
    for (int off = 32; off >= 1; off >>= 1) {
        s  += __shfl_down(s, off);
        s2 += __shfl_down(s2, off);
    }
    __shared__ float red[8];
    int wid = tid >> 6, lane = tid & 63;
    if (lane == 0) { red[wid] = s; red[wid + 4] = s2; }
    __syncthreads();
    float ts  = red[0] + red[1] + red[2] + red[3];
    float ts2 = red[4] + red[5] + red[6] + red[7];
    float mu  = ts * (1.0f / CDIM);
    float var = ts2 * (1.0f / CDIM) - mu * mu;
    float rstd = rsqrtf(var + 1e-5f);
    float4 gv = *(const float4*)(g + tid * 4);
    float4 bv = *(const float4*)(b + tid * 4);
    unsigned short o4[4];
    o4[0] = f2bf((v.x - mu) * rstd * gv.x + bv.x);
    o4[1] = f2bf((v.y - mu) * rstd * gv.y + bv.y);
    o4[2] = f2bf((v.z - mu) * rstd * gv.z + bv.z);
    o4[3] = f2bf((v.w - mu) * rstd * gv.w + bv.w);
    *(u16x4*)(out + (size_t)row * CDIM + tid * 4) = *(u16x4*)o4;
}

// ---- PREP: all 4 weight transposes + LN1, ONE launch ------------------------------
__global__ __launch_bounds__(256) void prep_kernel(
        const float* __restrict__ w_qkv, const float* __restrict__ w_out,
        const float* __restrict__ w_ff1, const float* __restrict__ w_ff2,
        const float* __restrict__ x, const float* __restrict__ ln1_g,
        const float* __restrict__ ln1_b,
        unsigned short* __restrict__ wqkvT, unsigned short* __restrict__ woutT,
        unsigned short* __restrict__ wff1T, unsigned short* __restrict__ wff2T,
        unsigned short* __restrict__ h_bf) {
    __shared__ float T[64][65];
    __shared__ float red[8];
    int bid = blockIdx.x;
    int tid = threadIdx.x;

    if (bid >= 3072) {
        const int row = bid - 3072;
        const float* xr = x + (size_t)row * CDIM;
        float4 v = *(const float4*)(xr + tid * 4);
        float s  = v.x + v.y + v.z + v.w;
        float s2 = v.x*v.x + v.y*v.y + v.z*v.z + v.w*v.w;
        #pragma unroll
        for (int off = 32; off >= 1; off >>= 1) {
            s  += __shfl_down(s, off);
            s2 += __shfl_down(s2, off);
        }
        int wid = tid >> 6, lane = tid & 63;
        if (lane == 0) { red[wid] = s; red[wid + 4] = s2; }
        __syncthreads();
        float ts  = red[0] + red[1] + red[2] + red[3];
        float ts2 = red[4] + red[5] + red[6] + red[7];
        float mu  = ts * (1.0f / CDIM);
        float var = ts2 * (1.0f / CDIM) - mu * mu;
        float rstd = rsqrtf(var + 1e-5f);
        float4 gv = *(const float4*)(ln1_g + tid * 4);
        float4 bv = *(const float4*)(ln1_b + tid * 4);
        unsigned short o4[4];
        o4[0] = f2bf((v.x - mu) * rstd * gv.x + bv.x);
        o4[1] = f2bf((v.y - mu) * rstd * gv.y + bv.y);
        o4[2] = f2bf((v.z - mu) * rstd * gv.z + bv.z);
        o4[3] = f2bf((v.w - mu) * rstd * gv.w + bv.w);
        *(u16x4*)(h_bf + (size_t)row * CDIM + tid * 4) = *(u16x4*)o4;
        return;
    }

    const float* W; unsigned short* Wt; int K, N, nbx;
    if (bid < 768)       {             W = w_qkv; Wt = wqkvT; K = 1024; N = 3072; nbx = 48; }
    else if (bid < 1024) { bid -= 768;  W = w_out; Wt = woutT; K = 1024; N = 1024; nbx = 16; }
    else if (bid < 2048) { bid -= 1024; W = w_ff1; Wt = wff1T; K = 1024; N = 4096; nbx = 64; }
    else                 { bid -= 2048; W = w_ff2; Wt = wff2T; K = 4096; N = 1024; nbx = 16; }
    const int n0 = (bid % nbx) * 64, k0 = (bid / nbx) * 64;

    int kr = tid >> 4;
    int nc = (tid & 15) * 4;
    #pragma unroll
    for (int i = 0; i < 4; ++i) {
        float4 v = *(const float4*)&W[(size_t)(k0 + kr + i*16) * N + (n0 + nc)];
        T[kr + i*16][nc + 0] = v.x;
        T[kr + i*16][nc + 1] = v.y;
        T[kr + i*16][nc + 2] = v.z;
        T[kr + i*16][nc + 3] = v.w;
    }
    __syncthreads();
    int n  = tid >> 2;
    int kb = (tid & 3) * 16;
    unsigned short tmp[16];
    #pragma unroll
    for (int i = 0; i < 16; ++i) tmp[i] = f2bf(T[kb + i][n]);
    unsigned short* dst = Wt + (size_t)(n0 + n) * K + (k0 + kb);
    *(int4*)dst       = *(int4*)&tmp[0];
    *(int4*)(dst + 8) = *(int4*)&tmp[8];
}

// ---- MFMA GEMM (TN) 256x256 tile, 8 waves, BK=32, 3-DEEP counted-vmcnt pipeline ---
template<int EPI>
__global__ __launch_bounds__(512) void gemm_kernel(const unsigned short* __restrict__ A,
                                                   const unsigned short* __restrict__ Bt,
                                                   const float* __restrict__ bias,
                                                   const float* __restrict__ res,
                                                   void* __restrict__ Cout,
                                                   unsigned short* __restrict__ kfrag_,
                                                   unsigned short* __restrict__ vfrag_,
                                                   int M, int N, int K,
                                                   int nxc, int xcw, int xrw) {
    __shared__ __align__(16) unsigned short As[3 * 8192];   // 3 x 16 KB (256 x 32)
    __shared__ __align__(16) unsigned short Bs[3 * 8192];   // 3 x 16 KB (256 x 32)
    const int tid = threadIdx.x;
    const int l   = tid & 63;
    const int w   = tid >> 6;                  // 0..7
    const int wr  = (w >> 2) * 128;            // wave rows: 0 or 128
    const int wcl = (w & 3) * 64;              // wave cols: 0/64/128/192
    const int lin = blockIdx.x;
    const int xcd = lin & 7;
    const int idx = lin >> 3;
    const int xc  = xcd % nxc, xr = xcd / nxc;
    const long brow = (long)(xr * xrw + idx / xcw) * 256;
    const long bcol = (long)(xc * xcw + idx % xcw) * 256;

    const int srow = tid >> 2;                                  // 0..127
    const int schk = ((tid & 3) ^ ((srow >> 1) & 3)) * 8;       // global elem offset
    const unsigned short* gA = A  + (size_t)(brow + srow) * K + schk;
    const unsigned short* gB = Bt + (size_t)(bcol + srow) * K + schk;

    f32x4 acc[8][4];
    #pragma unroll
    for (int m = 0; m < 8; ++m)
        #pragma unroll
        for (int n = 0; n < 4; ++n) acc[m][n] = (f32x4){0.f, 0.f, 0.f, 0.f};

    #define STAGE256(buf, koff_)                                                       \
        do {                                                                           \
            unsigned short* lA_ = As + (buf) * 8192 + tid * 8;                         \
            unsigned short* lB_ = Bs + (buf) * 8192 + tid * 8;                         \
            gload_lds16(gA + (koff_), lA_);                                            \
            gload_lds16(gA + (size_t)128 * K + (koff_), lA_ + 4096);                   \
            gload_lds16(gB + (koff_), lB_);                                            \
            gload_lds16(gB + (size_t)128 * K + (koff_), lB_ + 4096);                   \
        } while (0)

    STAGE256(0, 0);
    STAGE256(1, 32);

    int cur = 0;
    for (int k0 = 0; k0 < K; k0 += 32) {
        if (k0 + 32 < K) asm volatile("s_waitcnt vmcnt(4)" ::: "memory");
        else             asm volatile("s_waitcnt vmcnt(0)" ::: "memory");
        __builtin_amdgcn_s_barrier();
        asm volatile("" ::: "memory");   // no LDS read hoists above the barrier

        const unsigned short* cA = As + cur * 8192;
        const unsigned short* cB = Bs + cur * 8192;
        const int koff = ((l >> 4) ^ (((l & 15) >> 1) & 3)) * 8;
        bf16x8 af[8], bf[4];
        #pragma unroll
        for (int m = 0; m < 8; ++m)
            af[m] = *(const bf16x8*)&cA[(wr + m * 16 + (l & 15)) * 32 + koff];
        #pragma unroll
        for (int n = 0; n < 4; ++n)
            bf[n] = *(const bf16x8*)&cB[(wcl + n * 16 + (l & 15)) * 32 + koff];
        __builtin_amdgcn_s_setprio(1);
        #pragma unroll
        for (int m = 0; m < 8; ++m)
            #pragma unroll
            for (int n = 0; n < 4; ++n)
                acc[m][n] = __builtin_amdgcn_mfma_f32_16x16x32_bf16(af[m], bf[n], acc[m][n], 0, 0, 0);
        __builtin_amdgcn_s_setprio(0);

        if (k0 + 64 < K) {
            int nxt = cur + 2; if (nxt >= 3) nxt -= 3;
            STAGE256(nxt, k0 + 64);
        }
        cur = cur + 1; if (cur == 3) cur = 0;
    }
    #undef STAGE256

    const int reg = (int)(bcol >> 10);   // EPI==3: 0=Q, 1=K, 2=V (block-uniform; 256|1024)
    #pragma unroll
    for (int m = 0; m < 8; ++m) {
        const int rown = wr + m * 16 + (l >> 4) * 4;
        #pragma unroll
        for (int n = 0; n < 4; ++n) {
            const long col = bcol + wcl + n * 16 + (l & 15);
            const float bb = bias[col];
            #pragma unroll
            for (int r = 0; r < 4; ++r) {
                const long row = brow + rown + r;
                float v = acc[m][n][r] + bb;
                if (EPI == 1) {
                    v += res[row * N + col];
                    ((float*)Cout)[row * N + col] = v;
                } else if (EPI == 2) {
                    ((unsigned short*)Cout)[row * N + col] = f2bf(fast_gelu(v));
                } else if (EPI == 3) {
                    const unsigned short bv = f2bf(v);
                    if (reg == 0) {
                        ((unsigned short*)Cout)[row * 1024 + col] = bv;
                    } else {
                        const int dfull = (int)col - reg * 1024;
                        const int hh = dfull >> 6, dd = dfull & 63;
                        const int bb2 = (int)(row >> 11), tt = (int)(row & 2047);
                        const int jj = tt >> 6;
                        const size_t tb = ((size_t)((bb2 * 16 + hh) * 32 + jj)) * 8;
                        if (reg == 1) {     // K: kc = sb*2+g; lane = lhi*16+llo
                            const int sb2 = (tt >> 4) & 3, llo = tt & 15;
                            const int gg2 = dd >> 5, lhi = (dd >> 3) & 3, ii = dd & 7;
                            kfrag_[(tb + sb2 * 2 + gg2) * 512 + (lhi * 16 + llo) * 8 + ii] = bv;
                        } else {            // V: vc = kb*4+db; lane = lhi*16+llo
                            const int kb2 = (tt >> 5) & 1, lhi = (tt >> 3) & 3, ii = tt & 7;
                            const int db2 = dd >> 4, llo = dd & 15;
                            vfrag_[(tb + kb2 * 4 + db2) * 512 + (lhi * 16 + llo) * 8 + ii] = bv;
                        }
                    }
                } else {
                    ((unsigned short*)Cout)[row * N + col] = f2bf(v);
                }
            }
        }
    }
}

// ---- MFMA GEMM (TN) 128x128 tile, 8 waves, within-block SPLIT-K x2 ----------------
template<int EPI>
__global__ __launch_bounds__(512) void gemmsk_kernel(const unsigned short* __restrict__ A,
                                                     const unsigned short* __restrict__ Bt,
                                                     const float* __restrict__ bias,
                                                     const float* __restrict__ res,
                                                     void* __restrict__ Cout,
                                                     int M, int N, int K,
                                                     int nxc, int xcw, int xrw) {
    __shared__ __align__(16) unsigned short smem[6 * 8192];  // 96 KB: 3x(16A+16B)
    unsigned short* As = smem;
    unsigned short* Bs = smem + 3 * 8192;
    const int tid = threadIdx.x;
    const int l   = tid & 63;
    const int w   = tid >> 6;                  // 0..7
    const int ks  = w >> 2;                    // k-slice 0/1
    const int wr  = ((w >> 1) & 1) * 64;       // quadrant rows: 0/64
    const int wc  = (w & 1) * 64;              // quadrant cols: 0/64
    const int lin = blockIdx.x;
    const int xcd = lin & 7;
    const int idx = lin >> 3;
    const int xc  = xcd % nxc, xr = xcd / nxc;
    const long brow = (long)(xr * xrw + idx / xcw) * 128;
    const long bcol = (long)(xc * xcw + idx % xcw) * 128;

    const int srow = tid >> 3;                                  // 0..63
    const int schk = ((tid & 7) ^ (srow & 7)) * 8;
    const unsigned short* gA = A  + (size_t)(brow + srow) * K + schk;
    const unsigned short* gB = Bt + (size_t)(bcol + srow) * K + schk;

    f32x4 acc[4][4];
    #pragma unroll
    for (int m = 0; m < 4; ++m)
        #pragma unroll
        for (int n = 0; n < 4; ++n) acc[m][n] = (f32x4){0.f, 0.f, 0.f, 0.f};

    #define STAGESK(buf, koff_)                                                        \
        do {                                                                           \
            unsigned short* lA_ = As + (buf) * 8192 + tid * 8;                         \
            unsigned short* lB_ = Bs + (buf) * 8192 + tid * 8;                         \
            gload_lds16(gA + (koff_), lA_);                                            \
            gload_lds16(gA + (size_t)64 * K + (koff_), lA_ + 4096);                    \
            gload_lds16(gB + (koff_), lB_);                                            \
            gload_lds16(gB + (size_t)64 * K + (koff_), lB_ + 4096);                    \
        } while (0)

    STAGESK(0, 0);
    STAGESK(1, 64);

    int cur = 0, t = 0;
    for (int k0 = 0; k0 < K; k0 += 64, ++t) {
        if (k0 + 64 < K) asm volatile("s_waitcnt vmcnt(4)" ::: "memory");
        else             asm volatile("s_waitcnt vmcnt(0)" ::: "memory");
        __builtin_amdgcn_s_barrier();
        asm volatile("" ::: "memory");

        if ((t & 1) == ks) {            // wave-uniform parity branch
            const unsigned short* cA = As + cur * 8192;
            const unsigned short* cB = Bs + cur * 8192;
            #pragma unroll
            for (int gg = 0; gg < 2; ++gg) {
                const int koff = ((gg * 4 + (l >> 4)) ^ (l & 7)) * 8;
                bf16x8 af[4], bf[4];
                #pragma unroll
                for (int m = 0; m < 4; ++m)
                    af[m] = *(const bf16x8*)&cA[(wr + m * 16 + (l & 15)) * 64 + koff];
                #pragma unroll
                for (int n = 0; n < 4; ++n)
                    bf[n] = *(const bf16x8*)&cB[(wc + n * 16 + (l & 15)) * 64 + koff];
                __builtin_amdgcn_s_setprio(1);
                #pragma unroll
                for (int m = 0; m < 4; ++m)
                    #pragma unroll
                    for (int n = 0; n < 4; ++n)
                        acc[m][n] = __builtin_amdgcn_mfma_f32_16x16x32_bf16(af[m], bf[n], acc[m][n], 0, 0, 0);
                __builtin_amdgcn_s_setprio(0);
            }
        }

        if (k0 + 128 < K) {
            int nxt = cur + 2; if (nxt >= 3) nxt -= 3;
            STAGESK(nxt, k0 + 128);
        }
        cur = cur + 1; if (cur == 3) cur = 0;
    }
    #undef STAGESK

    // ---- cross-wave K-reduce: ks=1 partials -> LDS, ks=0 adds ----
    __syncthreads();                           // all K-loop LDS reads drained
    float* red = (float*)smem;                 // 4 regions x 4096 f32 = 64 KB
    const int rgn = w & 3;
    if (ks == 1) {
        #pragma unroll
        for (int m = 0; m < 4; ++m)
            #pragma unroll
            for (int n = 0; n < 4; ++n)
                *(f32x4*)&red[rgn * 4096 + l * 64 + ((m * 4 + n) ^ (l & 15)) * 4] = acc[m][n];
    }
    __syncthreads();
    if (ks == 1) return;

    #pragma unroll
    for (int m = 0; m < 4; ++m)
        #pragma unroll
        for (int n = 0; n < 4; ++n) {
            f32x4 p = *(const f32x4*)&red[rgn * 4096 + l * 64 + ((m * 4 + n) ^ (l & 15)) * 4];
            acc[m][n] += p;
        }

    #pragma unroll
    for (int m = 0; m < 4; ++m) {
        const int rown = wr + m * 16 + (l >> 4) * 4;
        #pragma unroll
        for (int n = 0; n < 4; ++n) {
            const long col = bcol + wc + n * 16 + (l & 15);
            const float bb = bias[col];
            #pragma unroll
            for (int r = 0; r < 4; ++r) {
                const long row = brow + rown + r;
                float v = acc[m][n][r] + bb;
                if (EPI == 1) {
                    v += res[row * N + col];
                    ((float*)Cout)[row * N + col] = v;
                } else if (EPI == 2) {
                    ((unsigned short*)Cout)[row * N + col] = f2bf(fast_gelu(v));
                } else {
                    ((unsigned short*)Cout)[row * N + col] = f2bf(v);
                }
            }
        }
    }
}

// ------------- MFMA causal flash attention (swapped QK^T, in-lane softmax) ----------
// Q-BLOCKED x2: one wave handles the adjacent strip pair (2ss, 2ss+1) -- both have
// IDENTICAL jmax ((2ss)>>2 == (2ss+1)>>2), so K/V fragment loads are shared across
// 2x the scores. Softmax+PV run sequentially per strip through the same Ps buffer
// (single wave -> in-order LDS semantics via lgkmcnt).
// T13 defer-max: skip rescale when __all(rowmax <= mrow + 8) -- P bounded by 2^8.
#define QSCALE 0.18033688011112042f   // 0.125 * log2(e)
#define RTHR 8.0f

template<int NT>
__device__ __forceinline__ void softmax_pv(f32x4* sf, float& mrow, float& lrow,
                                           f32x4* o, const bf16x8* vf,
                                           unsigned short* Ps, const int q, const int g) {
    f32x4 mv = sf[0];
    #pragma unroll
    for (int i = 1; i < NT * 4; ++i)
        #pragma unroll
        for (int r = 0; r < 4; ++r) mv[r] = fmaxf(mv[r], sf[i][r]);
    float mloc = fmaxf(fmaxf(mv[0], mv[1]), fmaxf(mv[2], mv[3]));
    mloc = fmaxf(mloc, __shfl_xor(mloc, 16));
    mloc = fmaxf(mloc, __shfl_xor(mloc, 32));

    float mn;
    if (__all(mloc <= mrow + RTHR)) {
        mn = mrow;                     // T13: keep old max; P bounded by 2^RTHR
    } else {
        mn = fmaxf(mrow, mloc);
        const float alpha = exp2f(mrow - mn);
        mrow = mn;
        lrow *= alpha;
        float al[4];
        #pragma unroll
        for (int r = 0; r < 4; ++r) al[r] = __shfl(alpha, g * 4 + r);
        #pragma unroll
        for (int d = 0; d < 4; ++d)
            #pragma unroll
            for (int r = 0; r < 4; ++r) o[d][r] *= al[r];
    }

    float psum = 0.f;
    #pragma unroll
    for (int i = 0; i < NT * 4; ++i) {
        float p0 = exp2f(sf[i][0] - mn);
        float p1 = exp2f(sf[i][1] - mn);
        float p2 = exp2f(sf[i][2] - mn);
        float p3 = exp2f(sf[i][3] - mn);
        psum += (p0 + p1) + (p2 + p3);
        unsigned int pk0 = cvt_pk_bf16(p0, p1);
        unsigned int pk1 = cvt_pk_bf16(p2, p3);
        const int c16 = (i * 2 + (g >> 1)) ^ (q & 7);
        *(uint2*)((char*)Ps + q * 256 + c16 * 16 + (g & 1) * 8) = make_uint2(pk0, pk1);
    }
    psum += __shfl_xor(psum, 16);
    psum += __shfl_xor(psum, 32);
    lrow += psum;

    __builtin_amdgcn_s_setprio(1);
    #pragma unroll
    for (int kb = 0; kb < NT * 2; ++kb) {
        const int c16 = (kb * 4 + g) ^ (q & 7);
        bf16x8 pa = *(const bf16x8*)((const char*)Ps + q * 256 + c16 * 16);
        #pragma unroll
        for (int db = 0; db < 4; ++db)
            o[db] = __builtin_amdgcn_mfma_f32_16x16x32_bf16(pa, vf[kb * 4 + db], o[db], 0, 0, 0);
    }
    __builtin_amdgcn_s_setprio(0);
}

__global__ __launch_bounds__(64) void attn_kernel(const unsigned short* __restrict__ qbuf,
                                                  const unsigned short* __restrict__ kfrag,
                                                  const unsigned short* __restrict__ vfrag,
                                                  unsigned short* __restrict__ out) {
    __shared__ __align__(16) unsigned short Ps[16 * 128];   // [q][s], reused per strip

    const int l    = threadIdx.x;
    const int q    = l & 15;                   // lane's softmax row
    const int g    = l >> 4;                   // lane group 0..3
    const int lin  = blockIdx.x;
    const int xcd  = lin & 7;
    const int rest = lin >> 3;
    const int h    = xcd + 8 * (rest & 1);
    const int b    = (rest >> 1) & 1;
    const int ss     = 63 - (rest >> 2);       // strip pair index (longest first)
    const int strip0 = ss * 2;                 // strips strip0, strip0+1
    const int jmax   = ss >> 1;                // == strip0>>2 == (strip0+1)>>2
    const size_t rowbase = (size_t)b * TSEQ;
    const int bh = b * NH + h;
    const int qgA = strip0 * 16 + q;
    const int qgB = qgA + 16;

    const unsigned short* kfb = kfrag + (size_t)bh * 32 * 8 * 512;
    const unsigned short* vfb = vfrag + (size_t)bh * 32 * 8 * 512;

    bf16x8 aqA0, aqA1, aqB0, aqB1;
    {
        const unsigned short* qpA = qbuf + (rowbase + qgA) * 1024 + h * 64 + g * 8;
        const unsigned short* qpB = qpA + (size_t)16 * 1024;
        bf16x8 t0 = *(const bf16x8*)qpA;
        bf16x8 t1 = *(const bf16x8*)(qpA + 32);
        bf16x8 t2 = *(const bf16x8*)qpB;
        bf16x8 t3 = *(const bf16x8*)(qpB + 32);
        #pragma unroll
        for (int i = 0; i < 8; ++i) {
            aqA0[i] = (short)f2bf(bf2f((unsigned short)t0[i]) * QSCALE);
            aqA1[i] = (short)f2bf(bf2f((unsigned short)t1[i]) * QSCALE);
            aqB0[i] = (short)f2bf(bf2f((unsigned short)t2[i]) * QSCALE);
            aqB1[i] = (short)f2bf(bf2f((unsigned short)t3[i]) * QSCALE);
        }
    }

    float mrA = -INFINITY, lrA = 0.f, mrB = -INFINITY, lrB = 0.f;
    f32x4 oA[4], oB[4];
    #pragma unroll
    for (int d = 0; d < 4; ++d) { oA[d] = (f32x4){0.f,0.f,0.f,0.f}; oB[d] = (f32x4){0.f,0.f,0.f,0.f}; }

    for (int j = 0; j + 1 <= jmax; j += 2) {
        const bool diag2 = (j + 1 == jmax);

        bf16x8 kf[16];
        #pragma unroll
        for (int t = 0; t < 2; ++t)
            #pragma unroll
            for (int sb = 0; sb < 4; ++sb) {
                const unsigned short* kp = kfb + (size_t)((j + t) * 8 + sb * 2) * 512 + l * 8;
                kf[t * 8 + sb * 2]     = *(const bf16x8*)kp;
                kf[t * 8 + sb * 2 + 1] = *(const bf16x8*)(kp + 512);
            }

        f32x4 sfA[8], sfB[8];
        __builtin_amdgcn_s_setprio(1);
        #pragma unroll
        for (int t = 0; t < 2; ++t)
            #pragma unroll
            for (int sb = 0; sb < 4; ++sb) {
                f32x4 a = (f32x4){0.f, 0.f, 0.f, 0.f};
                a = __builtin_amdgcn_mfma_f32_16x16x32_bf16(kf[t*8 + sb*2],     aqA0, a, 0, 0, 0);
                a = __builtin_amdgcn_mfma_f32_16x16x32_bf16(kf[t*8 + sb*2 + 1], aqA1, a, 0, 0, 0);
                sfA[t*4 + sb] = a;
                f32x4 c = (f32x4){0.f, 0.f, 0.f, 0.f};
                c = __builtin_amdgcn_mfma_f32_16x16x32_bf16(kf[t*8 + sb*2],     aqB0, c, 0, 0, 0);
                c = __builtin_amdgcn_mfma_f32_16x16x32_bf16(kf[t*8 + sb*2 + 1], aqB1, c, 0, 0, 0);
                sfB[t*4 + sb] = c;
            }
        __builtin_amdgcn_s_setprio(0);

        bf16x8 vf[16];
        #pragma unroll
        for (int kb = 0; kb < 4; ++kb)
            #pragma unroll
            for (int db = 0; db < 4; ++db)
                vf[kb * 4 + db] = *(const bf16x8*)(vfb + (size_t)((j + (kb >> 1)) * 8 + (kb & 1) * 4 + db) * 512 + l * 8);

        if (diag2) {
            #pragma unroll
            for (int sb = 0; sb < 4; ++sb) {
                const int sg = (j + 1) * 64 + sb * 16 + 4 * g;
                #pragma unroll
                for (int r = 0; r < 4; ++r) {
                    if (sg + r > qgA) sfA[4 + sb][r] = -INFINITY;
                    if (sg + r > qgB) sfB[4 + sb][r] = -INFINITY;
                }
            }
        }

        softmax_pv<2>(sfA, mrA, lrA, oA, vf, Ps, q, g);
        softmax_pv<2>(sfB, mrB, lrB, oB, vf, Ps, q, g);
    }

    if ((jmax & 1) == 0) {
        const int j = jmax;
        bf16x8 kf[8];
        #pragma unroll
        for (int sb = 0; sb < 4; ++sb) {
            const unsigned short* kp = kfb + (size_t)(j * 8 + sb * 2) * 512 + l * 8;
            kf[sb * 2]     = *(const bf16x8*)kp;
            kf[sb * 2 + 1] = *(const bf16x8*)(kp + 512);
        }
        f32x4 sfA[4], sfB[4];
        __builtin_amdgcn_s_setprio(1);
        #pragma unroll
        for (int sb = 0; sb < 4; ++sb) {
            f32x4 a = (f32x4){0.f, 0.f, 0.f, 0.f};
            a = __builtin_amdgcn_mfma_f32_16x16x32_bf16(kf[sb*2],     aqA0, a, 0, 0, 0);
            a = __builtin_amdgcn_mfma_f32_16x16x32_bf16(kf[sb*2 + 1], aqA1, a, 0, 0, 0);
            sfA[sb] = a;
            f32x4 c = (f32x4){0.f, 0.f, 0.f, 0.f};
            c = __builtin_amdgcn_mfma_f32_16x16x32_bf16(kf[sb*2],     aqB0, c, 0, 0, 0);
            c = __builtin_amdgcn_mfma_f32_16x16x32_bf16(kf[sb*2 + 1], aqB1, c, 0, 0, 0);
            sfB[sb] = c;
        }
        __builtin_amdgcn_s_setprio(0);

        bf16x8 vf[8];
        #pragma unroll
        for (int kb = 0; kb < 2; ++kb)
            #pragma unroll
            for (int db = 0; db < 4; ++db)
                vf[kb * 4 + db] = *(const bf16x8*)(vfb + (size_t)(j * 8 + kb * 4 + db) * 512 + l * 8);

        #pragma unroll
        for (int sb = 0; sb < 4; ++sb) {
            const int sg = j * 64 + sb * 16 + 4 * g;
            #pragma unroll
            for (int r = 0; r < 4; ++r) {
                if (sg + r > qgA) sfA[sb][r] = -INFINITY;
                if (sg + r > qgB) sfB[sb][r] = -INFINITY;
            }
        }

        softmax_pv<1>(sfA, mrA, lrA, oA, vf, Ps, q, g);
        softmax_pv<1>(sfB, mrB, lrB, oB, vf, Ps, q, g);
    }

    // epilogue: strip A rows = strip0*16 + g*4+r, strip B rows +16; cols = q + d*16
    float linvA[4], linvB[4];
    #pragma unroll
    for (int r = 0; r < 4; ++r) {
        linvA[r] = 1.0f / __shfl(lrA, g * 4 + r);
        linvB[r] = 1.0f / __shfl(lrB, g * 4 + r);
    }
    #pragma unroll
    for (int r = 0; r < 4; ++r) {
        const size_t rbA = (rowbase + strip0 * 16 + g * 4 + r) * (size_t)CDIM + h * 64 + q;
        const size_t rbB = rbA + (size_t)16 * CDIM;
        #pragma unroll
        for (int d = 0; d < 4; ++d) {
            out[rbA + d * 16] = f2bf(oA[d][r] * linvA[r]);
            out[rbB + d * 16] = f2bf(oB[d][r] * linvB[r]);
        }
    }
}

extern "C" void kernel_launch(void* const* d_in, const int* in_sizes, int n_in,
                              void* d_out, int out_size, void* d_ws, size_t ws_size,
                              hipStream_t stream) {
    const float* x     = (const float*)d_in[0];
    const float* ln1_g = (const float*)d_in[1];
    const float* ln1_b = (const float*)d_in[2];
    const float* w_qkv = (const float*)d_in[3];
    const float* b_qkv = (const float*)d_in[4];
    const float* w_out = (const float*)d_in[5];
    const float* b_out = (const float*)d_in[6];
    const float* ln2_g = (const float*)d_in[7];
    const float* ln2_b = (const float*)d_in[8];
    const float* w_ff1 = (const float*)d_in[9];
    const float* b_ff1 = (const float*)d_in[10];
    const float* w_ff2 = (const float*)d_in[11];
    const float* b_ff2 = (const float*)d_in[12];
    float* out = (float*)d_out;

    char* wsb = (char*)d_ws;
    unsigned short* h_bf    = (unsigned short*)(wsb);                          // 8 MB
    unsigned short* qbuf    = (unsigned short*)(wsb + 8ll  * 1024 * 1024);     // 8 MB (Q only)
    unsigned short* attn_bf = (unsigned short*)(wsb + 32ll * 1024 * 1024);     // 8 MB
    float*          x1      = (float*)         (wsb + 40ll * 1024 * 1024);     // 16 MB
    unsigned short* kfrag   = (unsigned short*)(wsb + 40ll * 1024 * 1024);     // 8 MB (overlays x1, dead until step 4)
    unsigned short* vfrag   = (unsigned short*)(wsb + 48ll * 1024 * 1024);     // 8 MB (overlays x1, dead until step 4)
    unsigned short* wqkvT   = (unsigned short*)(wsb + 56ll * 1024 * 1024);     // 6 MB
    unsigned short* woutT   = (unsigned short*)(wsb + 62ll * 1024 * 1024);     // 2 MB
    unsigned short* wff1T   = (unsigned short*)(wsb + 64ll * 1024 * 1024);     // 8 MB
    unsigned short* wff2T   = (unsigned short*)(wsb + 72ll * 1024 * 1024);     // 8 MB
    unsigned short* ff1_bf  = (unsigned short*)(wsb + 8ll  * 1024 * 1024);     // 32 MB, overlays dead qbuf+attn

    // 0. PREP: all weight transposes + LN1 in ONE launch (7168 blocks)
    prep_kernel<<<7168, 256, 0, stream>>>(w_qkv, w_out, w_ff1, w_ff2,
                                          x, ln1_g, ln1_b,
                                          wqkvT, woutT, wff1T, wff2T, h_bf);
    // 2. qkv = h @ w_qkv + b  (256x256 tiles, 8 waves; Q->qbuf, K/V fragment-major)
    gemm_kernel<3><<<192, 512, 0, stream>>>(h_bf, wqkvT, b_qkv, nullptr, qbuf,
                                            kfrag, vfrag, ROWS, 3072, 1024, 4, 3, 8);
    // 3. causal flash attention -> bf16 (Q-blocked x2: strip pair per wave)
    attn_kernel<<<2048, 64, 0, stream>>>(qbuf, kfrag, vfrag, attn_bf);
    // 4. x1 = x + attn @ w_out + b  -> f32  (128x128, split-K x2; 256 blocks = 1/CU)
    gemmsk_kernel<1><<<256, 512, 0, stream>>>(attn_bf, woutT, b_out, x, x1,
                                              ROWS, 1024, 1024, 2, 4, 8);
    // 5. LN2 -> bf16
    ln_kernel<<<ROWS, 256, 0, stream>>>(x1, ln2_g, ln2_b, h_bf);
    // 6. ff1 = gelu(h @ w_ff1 + b)  -> bf16  (256x256 tiles, 8 waves)
    gemm_kernel<2><<<256, 512, 0, stream>>>(h_bf, wff1T, b_ff1, nullptr, ff1_bf,
                                            nullptr, nullptr, ROWS, 4096, 1024, 4, 4, 8);
    // 7. out = x1 + ff1 @ w_ff2 + b  -> f32  (128x128, split-K x2; 256 blocks = 1/CU)
    gemmsk_kernel<1><<<256, 512, 0, stream>>>(ff1_bf, wff2T, b_ff2, x1, (float*)out,
                                              ROWS, 1024, 4096, 2, 4, 8);
}

// Round 31
// 214.684 us; speedup vs baseline: 1.0230x; 1.0230x over previous
//
#include <hip/hip_runtime.h>
#include <hip/hip_bf16.h>
#include <math.h>

#define TSEQ 2048
#define BATCH 2
#define CDIM 1024
#define NH 16
#define HD 64
#define DFF 4096
#define ROWS (BATCH*TSEQ)   // 4096

typedef __attribute__((ext_vector_type(4))) float f32x4;
typedef __attribute__((ext_vector_type(8))) short bf16x8;   // 8 bf16 in 4 VGPRs
typedef __attribute__((ext_vector_type(4))) unsigned short u16x4;

__device__ __forceinline__ void gload_lds16(const void* g, void* l) {
    void* gv = const_cast<void*>(g);
    __builtin_amdgcn_global_load_lds((__attribute__((address_space(1))) void*)gv,
                                     (__attribute__((address_space(3))) void*)l, 16, 0, 0);
}

__device__ __forceinline__ unsigned short f2bf(float f) {
    unsigned int u = __float_as_uint(f);
    return (unsigned short)((u + 0x7FFFu + ((u >> 16) & 1u)) >> 16);
}
__device__ __forceinline__ float bf2f(unsigned short u) {
    return __uint_as_float((unsigned int)u << 16);
}
// packed f32x2 -> bf16x2 (low half = first arg); no builtin on gfx950 (T12)
__device__ __forceinline__ unsigned int cvt_pk_bf16(float lo, float hi) {
    unsigned int r;
    asm("v_cvt_pk_bf16_f32 %0, %1, %2" : "=v"(r) : "v"(lo), "v"(hi));
    return r;
}
// tanh-form GELU: v * sigmoid(1.59577*(v + 0.044715 v^3)); |err vs exact| < ~3e-4
__device__ __forceinline__ float fast_gelu(float v) {
    float u = fmaf(0.044715f * v * v, v, v);
    float e = __expf(-1.5957691216057308f * u);
    return v * __builtin_amdgcn_rcpf(1.0f + e);
}

// ------------------------------- LayerNorm -> bf16 --------------------------------
__global__ __launch_bounds__(256) void ln_kernel(const float* __restrict__ x,
                                                 const float* __restrict__ g,
                                                 const float* __restrict__ b,
                                                 unsigned short* __restrict__ out) {
    int row = blockIdx.x;
    int tid = threadIdx.x;
    const float* xr = x + (size_t)row * CDIM;
    float4 v = *(const float4*)(xr + tid * 4);
    float s  = v.x + v.y + v.z + v.w;
    float s2 = v.x*v.x + v.y*v.y + v.z*v.z + v.w*v.w;
    #pragma unroll
    for (int off = 32; off >= 1; off >>= 1) {
        s  += __shfl_down(s, off);
        s2 += __shfl_down(s2, off);
    }
    __shared__ float red[8];
    int wid = tid >> 6, lane = tid & 63;
    if (lane == 0) { red[wid] = s; red[wid + 4] = s2; }
    __syncthreads();
    float ts  = red[0] + red[1] + red[2] + red[3];
    float ts2 = red[4] + red[5] + red[6] + red[7];
    float mu  = ts * (1.0f / CDIM);
    float var = ts2 * (1.0f / CDIM) - mu * mu;
    float rstd = rsqrtf(var + 1e-5f);
    float4 gv = *(const float4*)(g + tid * 4);
    float4 bv = *(const float4*)(b + tid * 4);
    unsigned short o4[4];
    o4[0] = f2bf((v.x - mu) * rstd * gv.x + bv.x);
    o4[1] = f2bf((v.y - mu) * rstd * gv.y + bv.y);
    o4[2] = f2bf((v.z - mu) * rstd * gv.z + bv.z);
    o4[3] = f2bf((v.w - mu) * rstd * gv.w + bv.w);
    *(u16x4*)(out + (size_t)row * CDIM + tid * 4) = *(u16x4*)o4;
}

// ---- PREP: all 4 weight transposes + LN1, ONE launch ------------------------------
__global__ __launch_bounds__(256) void prep_kernel(
        const float* __restrict__ w_qkv, const float* __restrict__ w_out,
        const float* __restrict__ w_ff1, const float* __restrict__ w_ff2,
        const float* __restrict__ x, const float* __restrict__ ln1_g,
        const float* __restrict__ ln1_b,
        unsigned short* __restrict__ wqkvT, unsigned short* __restrict__ woutT,
        unsigned short* __restrict__ wff1T, unsigned short* __restrict__ wff2T,
        unsigned short* __restrict__ h_bf) {
    __shared__ float T[64][65];
    __shared__ float red[8];
    int bid = blockIdx.x;
    int tid = threadIdx.x;

    if (bid >= 3072) {
        const int row = bid - 3072;
        const float* xr = x + (size_t)row * CDIM;
        float4 v = *(const float4*)(xr + tid * 4);
        float s  = v.x + v.y + v.z + v.w;
        float s2 = v.x*v.x + v.y*v.y + v.z*v.z + v.w*v.w;
        #pragma unroll
        for (int off = 32; off >= 1; off >>= 1) {
            s  += __shfl_down(s, off);
            s2 += __shfl_down(s2, off);
        }
        int wid = tid >> 6, lane = tid & 63;
        if (lane == 0) { red[wid] = s; red[wid + 4] = s2; }
        __syncthreads();
        float ts  = red[0] + red[1] + red[2] + red[3];
        float ts2 = red[4] + red[5] + red[6] + red[7];
        float mu  = ts * (1.0f / CDIM);
        float var = ts2 * (1.0f / CDIM) - mu * mu;
        float rstd = rsqrtf(var + 1e-5f);
        float4 gv = *(const float4*)(ln1_g + tid * 4);
        float4 bv = *(const float4*)(ln1_b + tid * 4);
        unsigned short o4[4];
        o4[0] = f2bf((v.x - mu) * rstd * gv.x + bv.x);
        o4[1] = f2bf((v.y - mu) * rstd * gv.y + bv.y);
        o4[2] = f2bf((v.z - mu) * rstd * gv.z + bv.z);
        o4[3] = f2bf((v.w - mu) * rstd * gv.w + bv.w);
        *(u16x4*)(h_bf + (size_t)row * CDIM + tid * 4) = *(u16x4*)o4;
        return;
    }

    const float* W; unsigned short* Wt; int K, N, nbx;
    if (bid < 768)       {             W = w_qkv; Wt = wqkvT; K = 1024; N = 3072; nbx = 48; }
    else if (bid < 1024) { bid -= 768;  W = w_out; Wt = woutT; K = 1024; N = 1024; nbx = 16; }
    else if (bid < 2048) { bid -= 1024; W = w_ff1; Wt = wff1T; K = 1024; N = 4096; nbx = 64; }
    else                 { bid -= 2048; W = w_ff2; Wt = wff2T; K = 4096; N = 1024; nbx = 16; }
    const int n0 = (bid % nbx) * 64, k0 = (bid / nbx) * 64;

    int kr = tid >> 4;
    int nc = (tid & 15) * 4;
    #pragma unroll
    for (int i = 0; i < 4; ++i) {
        float4 v = *(const float4*)&W[(size_t)(k0 + kr + i*16) * N + (n0 + nc)];
        T[kr + i*16][nc + 0] = v.x;
        T[kr + i*16][nc + 1] = v.y;
        T[kr + i*16][nc + 2] = v.z;
        T[kr + i*16][nc + 3] = v.w;
    }
    __syncthreads();
    int n  = tid >> 2;
    int kb = (tid & 3) * 16;
    unsigned short tmp[16];
    #pragma unroll
    for (int i = 0; i < 16; ++i) tmp[i] = f2bf(T[kb + i][n]);
    unsigned short* dst = Wt + (size_t)(n0 + n) * K + (k0 + kb);
    *(int4*)dst       = *(int4*)&tmp[0];
    *(int4*)(dst + 8) = *(int4*)&tmp[8];
}

// ---- MFMA GEMM (TN) 256x256 tile, 8 waves, BK=32, 3-DEEP counted-vmcnt pipeline ---
template<int EPI>
__global__ __launch_bounds__(512) void gemm_kernel(const unsigned short* __restrict__ A,
                                                   const unsigned short* __restrict__ Bt,
                                                   const float* __restrict__ bias,
                                                   const float* __restrict__ res,
                                                   void* __restrict__ Cout,
                                                   unsigned short* __restrict__ kfrag_,
                                                   unsigned short* __restrict__ vfrag_,
                                                   int M, int N, int K,
                                                   int nxc, int xcw, int xrw) {
    __shared__ __align__(16) unsigned short As[3 * 8192];   // 3 x 16 KB (256 x 32)
    __shared__ __align__(16) unsigned short Bs[3 * 8192];   // 3 x 16 KB (256 x 32)
    const int tid = threadIdx.x;
    const int l   = tid & 63;
    const int w   = tid >> 6;                  // 0..7
    const int wr  = (w >> 2) * 128;            // wave rows: 0 or 128
    const int wcl = (w & 3) * 64;              // wave cols: 0/64/128/192
    const int lin = blockIdx.x;
    const int xcd = lin & 7;
    const int idx = lin >> 3;
    const int xc  = xcd % nxc, xr = xcd / nxc;
    const long brow = (long)(xr * xrw + idx / xcw) * 256;
    const long bcol = (long)(xc * xcw + idx % xcw) * 256;

    const int srow = tid >> 2;                                  // 0..127
    const int schk = ((tid & 3) ^ ((srow >> 1) & 3)) * 8;       // global elem offset
    const unsigned short* gA = A  + (size_t)(brow + srow) * K + schk;
    const unsigned short* gB = Bt + (size_t)(bcol + srow) * K + schk;

    f32x4 acc[8][4];
    #pragma unroll
    for (int m = 0; m < 8; ++m)
        #pragma unroll
        for (int n = 0; n < 4; ++n) acc[m][n] = (f32x4){0.f, 0.f, 0.f, 0.f};

    #define STAGE256(buf, koff_)                                                       \
        do {                                                                           \
            unsigned short* lA_ = As + (buf) * 8192 + tid * 8;                         \
            unsigned short* lB_ = Bs + (buf) * 8192 + tid * 8;                         \
            gload_lds16(gA + (koff_), lA_);                                            \
            gload_lds16(gA + (size_t)128 * K + (koff_), lA_ + 4096);                   \
            gload_lds16(gB + (koff_), lB_);                                            \
            gload_lds16(gB + (size_t)128 * K + (koff_), lB_ + 4096);                   \
        } while (0)

    STAGE256(0, 0);
    STAGE256(1, 32);

    int cur = 0;
    for (int k0 = 0; k0 < K; k0 += 32) {
        if (k0 + 32 < K) asm volatile("s_waitcnt vmcnt(4)" ::: "memory");
        else             asm volatile("s_waitcnt vmcnt(0)" ::: "memory");
        __builtin_amdgcn_s_barrier();
        asm volatile("" ::: "memory");   // no LDS read hoists above the barrier

        const unsigned short* cA = As + cur * 8192;
        const unsigned short* cB = Bs + cur * 8192;
        const int koff = ((l >> 4) ^ (((l & 15) >> 1) & 3)) * 8;
        bf16x8 af[8], bf[4];
        #pragma unroll
        for (int m = 0; m < 8; ++m)
            af[m] = *(const bf16x8*)&cA[(wr + m * 16 + (l & 15)) * 32 + koff];
        #pragma unroll
        for (int n = 0; n < 4; ++n)
            bf[n] = *(const bf16x8*)&cB[(wcl + n * 16 + (l & 15)) * 32 + koff];
        __builtin_amdgcn_s_setprio(1);
        #pragma unroll
        for (int m = 0; m < 8; ++m)
            #pragma unroll
            for (int n = 0; n < 4; ++n)
                acc[m][n] = __builtin_amdgcn_mfma_f32_16x16x32_bf16(af[m], bf[n], acc[m][n], 0, 0, 0);
        __builtin_amdgcn_s_setprio(0);

        if (k0 + 64 < K) {
            int nxt = cur + 2; if (nxt >= 3) nxt -= 3;
            STAGE256(nxt, k0 + 64);
        }
        cur = cur + 1; if (cur == 3) cur = 0;
    }
    #undef STAGE256

    const int reg = (int)(bcol >> 10);   // EPI==3: 0=Q, 1=K, 2=V (block-uniform; 256|1024)
    #pragma unroll
    for (int m = 0; m < 8; ++m) {
        const int rown = wr + m * 16 + (l >> 4) * 4;
        #pragma unroll
        for (int n = 0; n < 4; ++n) {
            const long col = bcol + wcl + n * 16 + (l & 15);
            const float bb = bias[col];
            #pragma unroll
            for (int r = 0; r < 4; ++r) {
                const long row = brow + rown + r;
                float v = acc[m][n][r] + bb;
                if (EPI == 1) {
                    v += res[row * N + col];
                    ((float*)Cout)[row * N + col] = v;
                } else if (EPI == 2) {
                    ((unsigned short*)Cout)[row * N + col] = f2bf(fast_gelu(v));
                } else if (EPI == 3) {
                    const unsigned short bv = f2bf(v);
                    if (reg == 0) {
                        ((unsigned short*)Cout)[row * 1024 + col] = bv;
                    } else {
                        const int dfull = (int)col - reg * 1024;
                        const int hh = dfull >> 6, dd = dfull & 63;
                        const int bb2 = (int)(row >> 11), tt = (int)(row & 2047);
                        const int jj = tt >> 6;
                        const size_t tb = ((size_t)((bb2 * 16 + hh) * 32 + jj)) * 8;
                        if (reg == 1) {     // K: kc = sb*2+g; lane = lhi*16+llo
                            const int sb2 = (tt >> 4) & 3, llo = tt & 15;
                            const int gg2 = dd >> 5, lhi = (dd >> 3) & 3, ii = dd & 7;
                            kfrag_[(tb + sb2 * 2 + gg2) * 512 + (lhi * 16 + llo) * 8 + ii] = bv;
                        } else {            // V: vc = kb*4+db; lane = lhi*16+llo
                            const int kb2 = (tt >> 5) & 1, lhi = (tt >> 3) & 3, ii = tt & 7;
                            const int db2 = dd >> 4, llo = dd & 15;
                            vfrag_[(tb + kb2 * 4 + db2) * 512 + (lhi * 16 + llo) * 8 + ii] = bv;
                        }
                    }
                } else {
                    ((unsigned short*)Cout)[row * N + col] = f2bf(v);
                }
            }
        }
    }
}

// ---- MFMA GEMM (TN) 128x128 tile, 8 waves, within-block SPLIT-K x2 ----------------
template<int EPI>
__global__ __launch_bounds__(512) void gemmsk_kernel(const unsigned short* __restrict__ A,
                                                     const unsigned short* __restrict__ Bt,
                                                     const float* __restrict__ bias,
                                                     const float* __restrict__ res,
                                                     void* __restrict__ Cout,
                                                     int M, int N, int K,
                                                     int nxc, int xcw, int xrw) {
    __shared__ __align__(16) unsigned short smem[6 * 8192];  // 96 KB: 3x(16A+16B)
    unsigned short* As = smem;
    unsigned short* Bs = smem + 3 * 8192;
    const int tid = threadIdx.x;
    const int l   = tid & 63;
    const int w   = tid >> 6;                  // 0..7
    const int ks  = w >> 2;                    // k-slice 0/1
    const int wr  = ((w >> 1) & 1) * 64;       // quadrant rows: 0/64
    const int wc  = (w & 1) * 64;              // quadrant cols: 0/64
    const int lin = blockIdx.x;
    const int xcd = lin & 7;
    const int idx = lin >> 3;
    const int xc  = xcd % nxc, xr = xcd / nxc;
    const long brow = (long)(xr * xrw + idx / xcw) * 128;
    const long bcol = (long)(xc * xcw + idx % xcw) * 128;

    const int srow = tid >> 3;                                  // 0..63
    const int schk = ((tid & 7) ^ (srow & 7)) * 8;
    const unsigned short* gA = A  + (size_t)(brow + srow) * K + schk;
    const unsigned short* gB = Bt + (size_t)(bcol + srow) * K + schk;

    f32x4 acc[4][4];
    #pragma unroll
    for (int m = 0; m < 4; ++m)
        #pragma unroll
        for (int n = 0; n < 4; ++n) acc[m][n] = (f32x4){0.f, 0.f, 0.f, 0.f};

    #define STAGESK(buf, koff_)                                                        \
        do {                                                                           \
            unsigned short* lA_ = As + (buf) * 8192 + tid * 8;                         \
            unsigned short* lB_ = Bs + (buf) * 8192 + tid * 8;                         \
            gload_lds16(gA + (koff_), lA_);                                            \
            gload_lds16(gA + (size_t)64 * K + (koff_), lA_ + 4096);                    \
            gload_lds16(gB + (koff_), lB_);                                            \
            gload_lds16(gB + (size_t)64 * K + (koff_), lB_ + 4096);                    \
        } while (0)

    STAGESK(0, 0);
    STAGESK(1, 64);

    int cur = 0, t = 0;
    for (int k0 = 0; k0 < K; k0 += 64, ++t) {
        if (k0 + 64 < K) asm volatile("s_waitcnt vmcnt(4)" ::: "memory");
        else             asm volatile("s_waitcnt vmcnt(0)" ::: "memory");
        __builtin_amdgcn_s_barrier();
        asm volatile("" ::: "memory");

        if ((t & 1) == ks) {            // wave-uniform parity branch
            const unsigned short* cA = As + cur * 8192;
            const unsigned short* cB = Bs + cur * 8192;
            #pragma unroll
            for (int gg = 0; gg < 2; ++gg) {
                const int koff = ((gg * 4 + (l >> 4)) ^ (l & 7)) * 8;
                bf16x8 af[4], bf[4];
                #pragma unroll
                for (int m = 0; m < 4; ++m)
                    af[m] = *(const bf16x8*)&cA[(wr + m * 16 + (l & 15)) * 64 + koff];
                #pragma unroll
                for (int n = 0; n < 4; ++n)
                    bf[n] = *(const bf16x8*)&cB[(wc + n * 16 + (l & 15)) * 64 + koff];
                __builtin_amdgcn_s_setprio(1);
                #pragma unroll
                for (int m = 0; m < 4; ++m)
                    #pragma unroll
                    for (int n = 0; n < 4; ++n)
                        acc[m][n] = __builtin_amdgcn_mfma_f32_16x16x32_bf16(af[m], bf[n], acc[m][n], 0, 0, 0);
                __builtin_amdgcn_s_setprio(0);
            }
        }

        if (k0 + 128 < K) {
            int nxt = cur + 2; if (nxt >= 3) nxt -= 3;
            STAGESK(nxt, k0 + 128);
        }
        cur = cur + 1; if (cur == 3) cur = 0;
    }
    #undef STAGESK

    // ---- cross-wave K-reduce: ks=1 partials -> LDS, ks=0 adds ----
    __syncthreads();                           // all K-loop LDS reads drained
    float* red = (float*)smem;                 // 4 regions x 4096 f32 = 64 KB
    const int rgn = w & 3;
    if (ks == 1) {
        #pragma unroll
        for (int m = 0; m < 4; ++m)
            #pragma unroll
            for (int n = 0; n < 4; ++n)
                *(f32x4*)&red[rgn * 4096 + l * 64 + ((m * 4 + n) ^ (l & 15)) * 4] = acc[m][n];
    }
    __syncthreads();
    if (ks == 1) return;

    #pragma unroll
    for (int m = 0; m < 4; ++m)
        #pragma unroll
        for (int n = 0; n < 4; ++n) {
            f32x4 p = *(const f32x4*)&red[rgn * 4096 + l * 64 + ((m * 4 + n) ^ (l & 15)) * 4];
            acc[m][n] += p;
        }

    #pragma unroll
    for (int m = 0; m < 4; ++m) {
        const int rown = wr + m * 16 + (l >> 4) * 4;
        #pragma unroll
        for (int n = 0; n < 4; ++n) {
            const long col = bcol + wc + n * 16 + (l & 15);
            const float bb = bias[col];
            #pragma unroll
            for (int r = 0; r < 4; ++r) {
                const long row = brow + rown + r;
                float v = acc[m][n][r] + bb;
                if (EPI == 1) {
                    v += res[row * N + col];
                    ((float*)Cout)[row * N + col] = v;
                } else if (EPI == 2) {
                    ((unsigned short*)Cout)[row * N + col] = f2bf(fast_gelu(v));
                } else {
                    ((unsigned short*)Cout)[row * N + col] = f2bf(v);
                }
            }
        }
    }
}

// ------------- MFMA causal flash attention (swapped QK^T, in-lane softmax) ----------
// Q from compact qbuf; K/V from fragment-major kfrag/vfrag.
// T13 defer-max: skip rescale when __all(rowmax <= mrow + 8) -- P bounded by 2^8.
#define QSCALE 0.18033688011112042f   // 0.125 * log2(e)
#define RTHR 8.0f
__global__ __launch_bounds__(64) void attn_kernel(const unsigned short* __restrict__ qbuf,
                                                  const unsigned short* __restrict__ kfrag,
                                                  const unsigned short* __restrict__ vfrag,
                                                  unsigned short* __restrict__ out) {
    __shared__ __align__(16) unsigned short Ps[16 * 128];   // [q][s], 16B-chunk swizzled

    const int l    = threadIdx.x;
    const int q    = l & 15;                   // lane's softmax row
    const int g    = l >> 4;                   // lane group 0..3
    const int lin  = blockIdx.x;
    const int xcd  = lin & 7;
    const int rest = lin >> 3;
    const int h    = xcd + 8 * (rest & 1);
    const int b    = (rest >> 1) & 1;
    const int strip = 127 - (rest >> 2);
    const int jmax  = strip >> 2;
    const size_t rowbase = (size_t)b * TSEQ;
    const int bh = b * NH + h;
    const int qglob = strip * 16 + q;

    const unsigned short* kfb = kfrag + (size_t)bh * 32 * 8 * 512;
    const unsigned short* vfb = vfrag + (size_t)bh * 32 * 8 * 512;

    bf16x8 aq0, aq1;
    {
        const unsigned short* qp = qbuf + (rowbase + qglob) * 1024 + h * 64 + g * 8;
        bf16x8 t0 = *(const bf16x8*)qp;
        bf16x8 t1 = *(const bf16x8*)(qp + 32);
        #pragma unroll
        for (int i = 0; i < 8; ++i) {
            aq0[i] = (short)f2bf(bf2f((unsigned short)t0[i]) * QSCALE);
            aq1[i] = (short)f2bf(bf2f((unsigned short)t1[i]) * QSCALE);
        }
    }

    float mrow = -INFINITY, lrow = 0.f;
    f32x4 o[4];
    #pragma unroll
    for (int d = 0; d < 4; ++d) o[d] = (f32x4){0.f, 0.f, 0.f, 0.f};

    for (int j = 0; j + 1 <= jmax; j += 2) {
        const bool diag2 = (j + 1 == jmax);

        bf16x8 kf[16];
        #pragma unroll
        for (int t = 0; t < 2; ++t)
            #pragma unroll
            for (int sb = 0; sb < 4; ++sb) {
                const unsigned short* kp = kfb + (size_t)((j + t) * 8 + sb * 2) * 512 + l * 8;
                kf[t * 8 + sb * 2]     = *(const bf16x8*)kp;
                kf[t * 8 + sb * 2 + 1] = *(const bf16x8*)(kp + 512);
            }

        f32x4 sf[8];
        __builtin_amdgcn_s_setprio(1);
        #pragma unroll
        for (int t = 0; t < 2; ++t)
            #pragma unroll
            for (int sb = 0; sb < 4; ++sb) {
                f32x4 acc = (f32x4){0.f, 0.f, 0.f, 0.f};
                acc = __builtin_amdgcn_mfma_f32_16x16x32_bf16(kf[t*8 + sb*2],     aq0, acc, 0, 0, 0);
                acc = __builtin_amdgcn_mfma_f32_16x16x32_bf16(kf[t*8 + sb*2 + 1], aq1, acc, 0, 0, 0);
                sf[t*4 + sb] = acc;
            }
        __builtin_amdgcn_s_setprio(0);

        bf16x8 vf[16];
        #pragma unroll
        for (int kb = 0; kb < 4; ++kb)
            #pragma unroll
            for (int db = 0; db < 4; ++db)
                vf[kb * 4 + db] = *(const bf16x8*)(vfb + (size_t)((j + (kb >> 1)) * 8 + (kb & 1) * 4 + db) * 512 + l * 8);

        if (diag2) {
            #pragma unroll
            for (int sb = 0; sb < 4; ++sb) {
                const int sg = (j + 1) * 64 + sb * 16 + 4 * g;
                #pragma unroll
                for (int r = 0; r < 4; ++r)
                    if (sg + r > qglob) sf[4 + sb][r] = -INFINITY;
            }
        }

        f32x4 mv = sf[0];
        #pragma unroll
        for (int i = 1; i < 8; ++i)
            #pragma unroll
            for (int r = 0; r < 4; ++r) mv[r] = fmaxf(mv[r], sf[i][r]);
        float mloc = fmaxf(fmaxf(mv[0], mv[1]), fmaxf(mv[2], mv[3]));
        mloc = fmaxf(mloc, __shfl_xor(mloc, 16));
        mloc = fmaxf(mloc, __shfl_xor(mloc, 32));

        // T13 defer-max: skip rescale when the whole wave's rows stay within THR
        float mn;
        if (__all(mloc <= mrow + RTHR)) {
            mn = mrow;                     // keep old max; P bounded by 2^RTHR
        } else {
            mn = fmaxf(mrow, mloc);
            const float alpha = exp2f(mrow - mn);
            mrow = mn;
            lrow *= alpha;
            float al[4];
            #pragma unroll
            for (int r = 0; r < 4; ++r) al[r] = __shfl(alpha, g * 4 + r);
            #pragma unroll
            for (int d = 0; d < 4; ++d)
                #pragma unroll
                for (int r = 0; r < 4; ++r) o[d][r] *= al[r];
        }

        float psum = 0.f;
        #pragma unroll
        for (int i = 0; i < 8; ++i) {
            const int t = i >> 2, sb = i & 3;
            float p0 = exp2f(sf[i][0] - mn);
            float p1 = exp2f(sf[i][1] - mn);
            float p2 = exp2f(sf[i][2] - mn);
            float p3 = exp2f(sf[i][3] - mn);
            psum += (p0 + p1) + (p2 + p3);
            unsigned int pk0 = cvt_pk_bf16(p0, p1);
            unsigned int pk1 = cvt_pk_bf16(p2, p3);
            const int c16 = (t * 8 + sb * 2 + (g >> 1)) ^ (q & 7);
            *(uint2*)((char*)Ps + q * 256 + c16 * 16 + (g & 1) * 8) = make_uint2(pk0, pk1);
        }
        psum += __shfl_xor(psum, 16);
        psum += __shfl_xor(psum, 32);
        lrow += psum;

        __builtin_amdgcn_s_setprio(1);
        #pragma unroll
        for (int kb = 0; kb < 4; ++kb) {
            const int c16 = (kb * 4 + g) ^ (q & 7);
            bf16x8 pa = *(const bf16x8*)((const char*)Ps + q * 256 + c16 * 16);
            #pragma unroll
            for (int db = 0; db < 4; ++db)
                o[db] = __builtin_amdgcn_mfma_f32_16x16x32_bf16(pa, vf[kb * 4 + db], o[db], 0, 0, 0);
        }
        __builtin_amdgcn_s_setprio(0);
    }

    if ((jmax & 1) == 0) {
        const int j = jmax;
        bf16x8 kf[8];
        #pragma unroll
        for (int sb = 0; sb < 4; ++sb) {
            const unsigned short* kp = kfb + (size_t)(j * 8 + sb * 2) * 512 + l * 8;
            kf[sb * 2]     = *(const bf16x8*)kp;
            kf[sb * 2 + 1] = *(const bf16x8*)(kp + 512);
        }
        f32x4 sf[4];
        __builtin_amdgcn_s_setprio(1);
        #pragma unroll
        for (int sb = 0; sb < 4; ++sb) {
            f32x4 acc = (f32x4){0.f, 0.f, 0.f, 0.f};
            acc = __builtin_amdgcn_mfma_f32_16x16x32_bf16(kf[sb*2],     aq0, acc, 0, 0, 0);
            acc = __builtin_amdgcn_mfma_f32_16x16x32_bf16(kf[sb*2 + 1], aq1, acc, 0, 0, 0);
            sf[sb] = acc;
        }
        __builtin_amdgcn_s_setprio(0);

        bf16x8 vf[8];
        #pragma unroll
        for (int kb = 0; kb < 2; ++kb)
            #pragma unroll
            for (int db = 0; db < 4; ++db)
                vf[kb * 4 + db] = *(const bf16x8*)(vfb + (size_t)(j * 8 + kb * 4 + db) * 512 + l * 8);

        #pragma unroll
        for (int sb = 0; sb < 4; ++sb) {
            const int sg = j * 64 + sb * 16 + 4 * g;
            #pragma unroll
            for (int r = 0; r < 4; ++r)
                if (sg + r > qglob) sf[sb][r] = -INFINITY;
        }

        f32x4 mv = sf[0];
        #pragma unroll
        for (int i = 1; i < 4; ++i)
            #pragma unroll
            for (int r = 0; r < 4; ++r) mv[r] = fmaxf(mv[r], sf[i][r]);
        float mloc = fmaxf(fmaxf(mv[0], mv[1]), fmaxf(mv[2], mv[3]));
        mloc = fmaxf(mloc, __shfl_xor(mloc, 16));
        mloc = fmaxf(mloc, __shfl_xor(mloc, 32));

        float mn;
        if (__all(mloc <= mrow + RTHR)) {
            mn = mrow;
        } else {
            mn = fmaxf(mrow, mloc);
            const float alpha = exp2f(mrow - mn);
            mrow = mn;
            lrow *= alpha;
            float al[4];
            #pragma unroll
            for (int r = 0; r < 4; ++r) al[r] = __shfl(alpha, g * 4 + r);
            #pragma unroll
            for (int d = 0; d < 4; ++d)
                #pragma unroll
                for (int r = 0; r < 4; ++r) o[d][r] *= al[r];
        }

        float psum = 0.f;
        #pragma unroll
        for (int sb = 0; sb < 4; ++sb) {
            float p0 = exp2f(sf[sb][0] - mn);
            float p1 = exp2f(sf[sb][1] - mn);
            float p2 = exp2f(sf[sb][2] - mn);
            float p3 = exp2f(sf[sb][3] - mn);
            psum += (p0 + p1) + (p2 + p3);
            unsigned int pk0 = cvt_pk_bf16(p0, p1);
            unsigned int pk1 = cvt_pk_bf16(p2, p3);
            const int c16 = (sb * 2 + (g >> 1)) ^ (q & 7);
            *(uint2*)((char*)Ps + q * 256 + c16 * 16 + (g & 1) * 8) = make_uint2(pk0, pk1);
        }
        psum += __shfl_xor(psum, 16);
        psum += __shfl_xor(psum, 32);
        lrow += psum;

        __builtin_amdgcn_s_setprio(1);
        #pragma unroll
        for (int kb = 0; kb < 2; ++kb) {
            const int c16 = (kb * 4 + g) ^ (q & 7);
            bf16x8 pa = *(const bf16x8*)((const char*)Ps + q * 256 + c16 * 16);
            #pragma unroll
            for (int db = 0; db < 4; ++db)
                o[db] = __builtin_amdgcn_mfma_f32_16x16x32_bf16(pa, vf[kb * 4 + db], o[db], 0, 0, 0);
        }
        __builtin_amdgcn_s_setprio(0);
    }

    // epilogue: O rows = g*4+r, cols = q + db*16
    float linv[4];
    #pragma unroll
    for (int r = 0; r < 4; ++r) linv[r] = 1.0f / __shfl(lrow, g * 4 + r);
    #pragma unroll
    for (int r = 0; r < 4; ++r) {
        const size_t rb = (rowbase + strip * 16 + g * 4 + r) * (size_t)CDIM + h * 64 + q;
        #pragma unroll
        for (int d = 0; d < 4; ++d)
            out[rb + d * 16] = f2bf(o[d][r] * linv[r]);
    }
}

extern "C" void kernel_launch(void* const* d_in, const int* in_sizes, int n_in,
                              void* d_out, int out_size, void* d_ws, size_t ws_size,
                              hipStream_t stream) {
    const float* x     = (const float*)d_in[0];
    const float* ln1_g = (const float*)d_in[1];
    const float* ln1_b = (const float*)d_in[2];
    const float* w_qkv = (const float*)d_in[3];
    const float* b_qkv = (const float*)d_in[4];
    const float* w_out = (const float*)d_in[5];
    const float* b_out = (const float*)d_in[6];
    const float* ln2_g = (const float*)d_in[7];
    const float* ln2_b = (const float*)d_in[8];
    const float* w_ff1 = (const float*)d_in[9];
    const float* b_ff1 = (const float*)d_in[10];
    const float* w_ff2 = (const float*)d_in[11];
    const float* b_ff2 = (const float*)d_in[12];
    float* out = (float*)d_out;

    char* wsb = (char*)d_ws;
    unsigned short* h_bf    = (unsigned short*)(wsb);                          // 8 MB
    unsigned short* qbuf    = (unsigned short*)(wsb + 8ll  * 1024 * 1024);     // 8 MB (Q only)
    unsigned short* attn_bf = (unsigned short*)(wsb + 32ll * 1024 * 1024);     // 8 MB
    float*          x1      = (float*)         (wsb + 40ll * 1024 * 1024);     // 16 MB
    unsigned short* kfrag   = (unsigned short*)(wsb + 40ll * 1024 * 1024);     // 8 MB (overlays x1, dead until step 4)
    unsigned short* vfrag   = (unsigned short*)(wsb + 48ll * 1024 * 1024);     // 8 MB (overlays x1, dead until step 4)
    unsigned short* wqkvT   = (unsigned short*)(wsb + 56ll * 1024 * 1024);     // 6 MB
    unsigned short* woutT   = (unsigned short*)(wsb + 62ll * 1024 * 1024);     // 2 MB
    unsigned short* wff1T   = (unsigned short*)(wsb + 64ll * 1024 * 1024);     // 8 MB
    unsigned short* wff2T   = (unsigned short*)(wsb + 72ll * 1024 * 1024);     // 8 MB
    unsigned short* ff1_bf  = (unsigned short*)(wsb + 8ll  * 1024 * 1024);     // 32 MB, overlays dead qbuf+attn

    // 0. PREP: all weight transposes + LN1 in ONE launch (7168 blocks)
    prep_kernel<<<7168, 256, 0, stream>>>(w_qkv, w_out, w_ff1, w_ff2,
                                          x, ln1_g, ln1_b,
                                          wqkvT, woutT, wff1T, wff2T, h_bf);
    // 2. qkv = h @ w_qkv + b  (256x256 tiles, 8 waves; Q->qbuf, K/V fragment-major)
    gemm_kernel<3><<<192, 512, 0, stream>>>(h_bf, wqkvT, b_qkv, nullptr, qbuf,
                                            kfrag, vfrag, ROWS, 3072, 1024, 4, 3, 8);
    // 3. causal flash attention -> bf16 (swapped QK^T, defer-max softmax)
    attn_kernel<<<4096, 64, 0, stream>>>(qbuf, kfrag, vfrag, attn_bf);
    // 4. x1 = x + attn @ w_out + b  -> f32  (128x128, split-K x2; 256 blocks = 1/CU)
    gemmsk_kernel<1><<<256, 512, 0, stream>>>(attn_bf, woutT, b_out, x, x1,
                                              ROWS, 1024, 1024, 2, 4, 8);
    // 5. LN2 -> bf16
    ln_kernel<<<ROWS, 256, 0, stream>>>(x1, ln2_g, ln2_b, h_bf);
    // 6. ff1 = gelu(h @ w_ff1 + b)  -> bf16  (256x256 tiles, 8 waves)
    gemm_kernel<2><<<256, 512, 0, stream>>>(h_bf, wff1T, b_ff1, nullptr, ff1_bf,
                                            nullptr, nullptr, ROWS, 4096, 1024, 4, 4, 8);
    // 7. out = x1 + ff1 @ w_ff2 + b  -> f32  (128x128, split-K x2; 256 blocks = 1/CU)
    gemmsk_kernel<1><<<256, 512, 0, stream>>>(ff1_bf, wff2T, b_ff2, x1, (float*)out,
                                              ROWS, 1024, 4096, 2, 4, 8);
}